// Round 11
// baseline (126.008 us; speedup 1.0000x reference)
//
#include <hip/hip_runtime.h>
#include <stdint.h>

// OrthogonalLinear: pyramid Givens circuit, n = m = 512, B = 256.
// T = 1021 layers; layer t has gates (i, i+1) for i = (t&1), (t&1)+2, ...,
// i <= min(t, 1020-t). theta index: k = (t+i)/2 + 1, idx = k(k-1)/2 + (k-1-i).
//
// Table W4 (d_ws), float4 units: pair p (layers t=2p, 2p+1) at [p*256,(p+1)*256).
// Quarter q in 0..3, lane L: idx = p*256 + q*64 + L:
//   q0 = (cE0,sE0,cE1,sE1)   even gates at wires 8L+0, 8L+2
//   q1 = (cE2,sE2,cE3,sE3)   even gates at wires 8L+4, 8L+6
//   q2 = (cO0,sO0,cO1,sO1)   odd  gates at wires 8L+1, 8L+3
//   q3 = (cO2,sO2,cU-1,sU)   odd gate at 8L+5; boundary gate (8L+7) stored
//                            as (c-1, s) so DPP's shifted-in 0 = identity.
// Block p=510 (128 float4, q=0/1, plain (c,s)) = final even layer t=1020.
//
// R11: the circuit is linear, so out = x * M_early * M_late. One kernel with
// 768 waves runs IN PARALLEL: waves 0..255 push x rows through layers
// 0..509 (pairs 0..254) -> T1; waves 256..767 push basis vectors e_u through
// layers 510..1020 (pairs 255..509 + final) -> rows of M_late. Serial depth
// per wave halves (510 -> 255 pairs). A small fp32 GEMM applies M_late+bias.

#define N_WIRES 512
#define BATCH   256
#define PAIRS   510
#define HALFP   255
#define PF      5                   // ring depth; 255 = 5 * 51
#define FINAL4  (PAIRS * 256)       // 130560
#define TOTAL4  (FINAL4 + 128)      // 130688
#define TOTAL2  (TOTAL4 * 2)        // 261376 float2 slots

// ---------------- kernel 1: fused f32 table build ----------------
__global__ __launch_bounds__(256) void fused_kernel(
    const float* __restrict__ thetas, float2* __restrict__ W2) {
  int tid = blockIdx.x * 256 + threadIdx.x;
  if (tid >= TOTAL2) return;
  float c = 1.0f, s = 0.0f;
  if (tid < PAIRS * 512) {
    int p = tid >> 9, r = tid & 511;
    int q = r >> 7, L = (r >> 1) & 63, e = r & 1, h = q >> 1;
    int t = 2 * p + h;
    int i = 8 * L + 4 * (q & 1) + 2 * e + h;
    if (i <= min(t, 1020 - t)) {
      int k = ((t + i) >> 1) + 1;
      int idx = ((k * (k - 1)) >> 1) + (k - 1 - i);
      __sincosf(thetas[idx], &s, &c);
    }
    if (q == 3 && e == 1) c -= 1.0f;   // boundary gate stored as (c-1, s)
  } else {
    int e = tid - PAIRS * 512;         // final even layer t = 1020
    int L = e >> 2, j = e & 3;
    if (8 * L + 2 * j == 0) __sincosf(thetas[130815], &s, &c);
  }
  W2[tid] = make_float2(c, s);
}

// ---------------- circuit core ----------------
template <int N>
__device__ __forceinline__ void wait_vm() {
  asm volatile("s_waitcnt vmcnt(%0)" ::"i"(N) : "memory");
}

__device__ __forceinline__ float dpp_shr1(float v) {  // lane i <- i-1; lane0 <- 0
  return __int_as_float(
      __builtin_amdgcn_mov_dpp(__float_as_int(v), 0x138, 0xF, 0xF, true));
}
__device__ __forceinline__ float dpp_shl1(float v) {  // lane i <- i+1; lane63 <- 0
  return __int_as_float(
      __builtin_amdgcn_mov_dpp(__float_as_int(v), 0x130, 0xF, 0xF, true));
}

// Packed Givens gate, in place: ab=(a,b), cs=(c,s) -> (c*a+s*b, c*b-s*a).
__device__ __forceinline__ void gate_pk2(float2 cs, float2& ab) {
  float2 t;
  asm("v_pk_mul_f32 %0, %1, %2 op_sel:[1,1] op_sel_hi:[1,0] neg_hi:[1,0]"
      : "=v"(t)
      : "v"(cs), "v"(ab));
  asm("v_pk_fma_f32 %0, %1, %0, %2 op_sel:[0,0,0] op_sel_hi:[0,1,1]"
      : "+v"(ab)
      : "v"(cs), "v"(t));
}

__device__ __forceinline__ void gate_s(float& a, float& b, float c, float s) {
  float na = fmaf(c, a, s * b);
  float nb = fmaf(c, b, -(s * a));
  a = na;
  b = nb;
}

__device__ __forceinline__ void pair_compute(float2& A, float2& B, float2& C,
                                             float2& D, const float4& q0,
                                             const float4& q1, const float4& q2,
                                             const float4& q3) {
  gate_pk2(make_float2(q0.x, q0.y), A);
  gate_pk2(make_float2(q0.z, q0.w), B);
  gate_pk2(make_float2(q1.x, q1.y), C);
  gate_pk2(make_float2(q1.z, q1.w), D);
  float cl_m1 = dpp_shr1(q3.z);   // left neighbor's (c-1); lane0 -> 0 = identity
  float sl    = dpp_shr1(q3.w);
  float rv0 = dpp_shl1(A.x);      // right neighbor's wire 8L+8 (post-even)
  float lv7 = dpp_shr1(D.y);      // left neighbor's wire 8L-1 (post-even)
  gate_s(A.y, B.x, q2.x, q2.y);
  gate_s(B.y, C.x, q2.z, q2.w);
  gate_s(C.y, D.x, q3.x, q3.y);
  float nv7 = fmaf(q3.w, rv0, fmaf(q3.z, D.y, D.y));   // c = 1 + q3.z
  float nv0 = fmaf(-sl, lv7, fmaf(cl_m1, A.x, A.x));   // c = 1 + cl_m1
  D.y = nv7;
  A.x = nv0;
}

// Run pairs [p0, p0+255) with a PF=5 register ring, uniform-SGPR addressing.
__device__ __forceinline__ void run_255(const float4* __restrict__ Wg, int p0,
                                        int lane, float2& A, float2& B,
                                        float2& C, float2& D) {
  const float4* pb = Wg + p0 * 256;   // wave-uniform -> SGPR base
  float4 R[PF][4];
#pragma unroll
  for (int s = 0; s < PF; ++s) {
    R[s][0] = pb[lane];
    R[s][1] = pb[64 + lane];
    R[s][2] = pb[128 + lane];
    R[s][3] = pb[192 + lane];
    pb += 256;
  }
  for (int blk = 0; blk < 50; ++blk) {
#pragma unroll
    for (int s = 0; s < PF; ++s) {
      wait_vm<16>();   // retire exactly the oldest pair's 4 loads
      pair_compute(A, B, C, D, R[s][0], R[s][1], R[s][2], R[s][3]);
      R[s][0] = pb[lane];
      R[s][1] = pb[64 + lane];
      R[s][2] = pb[128 + lane];
      R[s][3] = pb[192 + lane];
      pb += 256;
    }
  }
  wait_vm<0>();
#pragma unroll
  for (int s = 0; s < PF; ++s)
    pair_compute(A, B, C, D, R[s][0], R[s][1], R[s][2], R[s][3]);
}

// ---------------- kernel 2: two-phase circuit (768 waves) ----------------
__global__ __launch_bounds__(64, 1) void phase_kernel(
    const float* __restrict__ x, const float* __restrict__ W,
    float* __restrict__ T1, float* __restrict__ ML) {
  const int lane = threadIdx.x;
  const int b = blockIdx.x;
  const bool late = (b >= BATCH);
  const float4* __restrict__ Wg = (const float4*)W;

  float2 A, B, C, D;
  if (!late) {
    const float4* xr = (const float4*)(x + b * N_WIRES) + lane * 2;
    float4 x0 = xr[0], x1 = xr[1];
    A = make_float2(x0.x, x0.y); B = make_float2(x0.z, x0.w);
    C = make_float2(x1.x, x1.y); D = make_float2(x1.z, x1.w);
    run_255(Wg, 0, lane, A, B, C, D);
    float* tr = T1 + b * N_WIRES + lane * 8;
    *(float4*)tr = make_float4(A.x, A.y, B.x, B.y);
    *(float4*)(tr + 4) = make_float4(C.x, C.y, D.x, D.y);
  } else {
    const int u = b - BATCH;
    const int base = lane * 8;
    A = make_float2(base + 0 == u ? 1.f : 0.f, base + 1 == u ? 1.f : 0.f);
    B = make_float2(base + 2 == u ? 1.f : 0.f, base + 3 == u ? 1.f : 0.f);
    C = make_float2(base + 4 == u ? 1.f : 0.f, base + 5 == u ? 1.f : 0.f);
    D = make_float2(base + 6 == u ? 1.f : 0.f, base + 7 == u ? 1.f : 0.f);
    run_255(Wg, HALFP, lane, A, B, C, D);
    // final even layer t = 1020 (pre-masked identity except gate 0)
    float4 f0 = Wg[FINAL4 + lane];
    float4 f1 = Wg[FINAL4 + 64 + lane];
    gate_pk2(make_float2(f0.x, f0.y), A);
    gate_pk2(make_float2(f0.z, f0.w), B);
    gate_pk2(make_float2(f1.x, f1.y), C);
    gate_pk2(make_float2(f1.z, f1.w), D);
    float* mr = ML + u * N_WIRES + lane * 8;
    *(float4*)mr = make_float4(A.x, A.y, B.x, B.y);
    *(float4*)(mr + 4) = make_float4(C.x, C.y, D.x, D.y);
  }
}

// ---------------- kernel 3: out = T1 * ML + bias (fp32) ----------------
__global__ __launch_bounds__(256) void gemm_kernel(
    const float* __restrict__ T1, const float* __restrict__ ML,
    const float* __restrict__ bias, float* __restrict__ out) {
  __shared__ float a_s[1024];
  const int tid = threadIdx.x;
  const int half = tid >> 7, j = tid & 127;
  const int rbase = blockIdx.x * 2;
  for (int i = tid; i < 1024; i += 256) a_s[i] = T1[rbase * N_WIRES + i];
  __syncthreads();
  const float4* __restrict__ ML4 = (const float4*)ML;
  float4 acc = make_float4(0.f, 0.f, 0.f, 0.f);
#pragma unroll 8
  for (int u = 0; u < 512; ++u) {
    float a = a_s[half * 512 + u];
    float4 m = ML4[u * 128 + j];
    acc.x = fmaf(a, m.x, acc.x);
    acc.y = fmaf(a, m.y, acc.y);
    acc.z = fmaf(a, m.z, acc.z);
    acc.w = fmaf(a, m.w, acc.w);
  }
  float4 bv = ((const float4*)bias)[j];
  acc.x += bv.x; acc.y += bv.y; acc.z += bv.z; acc.w += bv.w;
  ((float4*)out)[(rbase + half) * 128 + j] = acc;
}

// ---------------- fallback: proven single-phase (R7 structure) -------------
__global__ __launch_bounds__(64, 1) void circuit_full(
    const float* __restrict__ x, const float* __restrict__ W,
    const float* __restrict__ bias, float* __restrict__ out) {
  const int lane = threadIdx.x;
  const int row = blockIdx.x;
  const float4* __restrict__ Wg = (const float4*)W;

  const float4* pb = Wg;
  float4 R[PF][4];
#pragma unroll
  for (int s = 0; s < PF; ++s) {
    R[s][0] = pb[lane]; R[s][1] = pb[64 + lane];
    R[s][2] = pb[128 + lane]; R[s][3] = pb[192 + lane];
    pb += 256;
  }
  const float4* xr = (const float4*)(x + row * N_WIRES) + lane * 2;
  float4 x0 = xr[0], x1 = xr[1];
  float2 A = make_float2(x0.x, x0.y), B = make_float2(x0.z, x0.w);
  float2 C = make_float2(x1.x, x1.y), D = make_float2(x1.z, x1.w);

  for (int blk = 0; blk < 101; ++blk) {   // 101*5 + 5 = 510
#pragma unroll
    for (int s = 0; s < PF; ++s) {
      wait_vm<16>();
      pair_compute(A, B, C, D, R[s][0], R[s][1], R[s][2], R[s][3]);
      R[s][0] = pb[lane]; R[s][1] = pb[64 + lane];
      R[s][2] = pb[128 + lane]; R[s][3] = pb[192 + lane];
      pb += 256;
    }
  }
  wait_vm<0>();
#pragma unroll
  for (int s = 0; s < PF; ++s)
    pair_compute(A, B, C, D, R[s][0], R[s][1], R[s][2], R[s][3]);

  float4 f0 = Wg[FINAL4 + lane];
  float4 f1 = Wg[FINAL4 + 64 + lane];
  gate_pk2(make_float2(f0.x, f0.y), A);
  gate_pk2(make_float2(f0.z, f0.w), B);
  gate_pk2(make_float2(f1.x, f1.y), C);
  gate_pk2(make_float2(f1.z, f1.w), D);

  const float* br = bias + lane * 8;
  float4 b0 = *(const float4*)(br);
  float4 b1 = *(const float4*)(br + 4);
  float* orow = out + row * N_WIRES + lane * 8;
  *(float4*)(orow) = make_float4(A.x + b0.x, A.y + b0.y, B.x + b0.z, B.y + b0.w);
  *(float4*)(orow + 4) = make_float4(C.x + b1.x, C.y + b1.y, D.x + b1.z, D.y + b1.w);
}

extern "C" void kernel_launch(void* const* d_in, const int* in_sizes, int n_in,
                              void* d_out, int out_size, void* d_ws,
                              size_t ws_size, hipStream_t stream) {
  const float* x = (const float*)d_in[0];       // (256, 512) f32
  const float* thetas = (const float*)d_in[1];  // (130816,) f32
  const float* bias = (const float*)d_in[2];    // (512,) f32
  float* out = (float*)d_out;                   // (256, 512) f32

  float* W = (float*)d_ws;                      // table: 130688 float4
  const size_t table_bytes = (size_t)TOTAL4 * 16;         // 2,091,008
  const size_t t1_bytes = (size_t)BATCH * N_WIRES * 4;    //   524,288
  const size_t ml_bytes = (size_t)N_WIRES * N_WIRES * 4;  // 1,048,576

  fused_kernel<<<TOTAL2 / 256, 256, 0, stream>>>(thetas, (float2*)W);

  if (ws_size >= table_bytes + t1_bytes + ml_bytes) {
    float* T1 = (float*)((char*)d_ws + table_bytes);
    float* ML = T1 + BATCH * N_WIRES;
    phase_kernel<<<BATCH + N_WIRES, 64, 0, stream>>>(x, W, T1, ML);
    gemm_kernel<<<BATCH / 2, 256, 0, stream>>>(T1, ML, bias, out);
  } else {
    circuit_full<<<BATCH, 64, 0, stream>>>(x, W, bias, out);
  }
}

// Round 12
// 120.158 us; speedup vs baseline: 1.0487x; 1.0487x over previous
//
#include <hip/hip_runtime.h>
#include <stdint.h>

// OrthogonalLinear: pyramid Givens circuit, n = m = 512, B = 256.
// T = 1021 layers; layer t has gates (i, i+1) for i = (t&1), (t&1)+2, ...,
// i <= min(t, 1020-t). theta index: k = (t+i)/2 + 1, idx = k(k-1)/2 + (k-1-i).
//
// Table W4 (d_ws), float4 units: pair p (layers t=2p, 2p+1) at [p*256,(p+1)*256).
// Quarter q in 0..3, lane L: idx = p*256 + q*64 + L:
//   q0 = (cE0,sE0,cE1,sE1)   even gates at wires 8L+0, 8L+2
//   q1 = (cE2,sE2,cE3,sE3)   even gates at wires 8L+4, 8L+6
//   q2 = (cO0,sO0,cO1,sO1)   odd  gates at wires 8L+1, 8L+3
//   q3 = (cO2,sO2,cU-1,sU)   odd gate at 8L+5; boundary gate (8L+7) stored
//                            as (c-1, s) so DPP's shifted-in 0 = identity.
// Block p=510 (128 float4, q=0/1, plain (c,s)) = final even layer t=1020.
//
// R12: out = x * M_early * M_late (circuit is linear). 192 blocks x 4 waves:
// blocks 0..63 push 4 x-rows each through pairs 0..254 -> T1; blocks 64..191
// push 4 basis rows each through pairs 255..509 + final -> M_late rows.
// Within a block the table is fetched ONCE per CU via global_load_lds
// (4-pair chunks, 16 loads split 4/wave, TRIPLE-buffered LDS, per-wave
// vmcnt(4) then barrier) so the per-CU L1/TA wall (~140 cyc/pair/wave,
// the R2-R11 limiter) is paid once for 4 waves, and DMA stays 2 chunks
// ahead of compute (R9's vmcnt(0)-before-barrier serialization fixed).
// Then a small fp32 GEMM applies M_late + bias.

#define N_WIRES 512
#define BATCH   256
#define PAIRS   510
#define SEGP    255                 // pairs per phase segment
#define CH      4                   // pairs per DMA chunk
#define NCH     63                  // full chunks; tail = 3 pairs in registers
#define CH4     (CH * 256)          // 1024 float4 = 16 KB per buffer
#define FINAL4  (PAIRS * 256)       // 130560
#define TOTAL4  (FINAL4 + 128)      // 130688
#define TOTAL2  (TOTAL4 * 2)        // 261376 float2 slots

// ---------------- kernel 1: fused f32 table build ----------------
__global__ __launch_bounds__(256) void fused_kernel(
    const float* __restrict__ thetas, float2* __restrict__ W2) {
  int tid = blockIdx.x * 256 + threadIdx.x;
  if (tid >= TOTAL2) return;
  float c = 1.0f, s = 0.0f;
  if (tid < PAIRS * 512) {
    int p = tid >> 9, r = tid & 511;
    int q = r >> 7, L = (r >> 1) & 63, e = r & 1, h = q >> 1;
    int t = 2 * p + h;
    int i = 8 * L + 4 * (q & 1) + 2 * e + h;
    if (i <= min(t, 1020 - t)) {
      int k = ((t + i) >> 1) + 1;
      int idx = ((k * (k - 1)) >> 1) + (k - 1 - i);
      __sincosf(thetas[idx], &s, &c);
    }
    if (q == 3 && e == 1) c -= 1.0f;   // boundary gate stored as (c-1, s)
  } else {
    int e = tid - PAIRS * 512;         // final even layer t = 1020
    int L = e >> 2, j = e & 3;
    if (8 * L + 2 * j == 0) __sincosf(thetas[130815], &s, &c);
  }
  W2[tid] = make_float2(c, s);
}

// ---------------- circuit core ----------------
template <int N>
__device__ __forceinline__ void wait_vm() {
  asm volatile("s_waitcnt vmcnt(%0)" ::"i"(N) : "memory");
}

__device__ __forceinline__ float dpp_shr1(float v) {  // lane i <- i-1; lane0 <- 0
  return __int_as_float(
      __builtin_amdgcn_mov_dpp(__float_as_int(v), 0x138, 0xF, 0xF, true));
}
__device__ __forceinline__ float dpp_shl1(float v) {  // lane i <- i+1; lane63 <- 0
  return __int_as_float(
      __builtin_amdgcn_mov_dpp(__float_as_int(v), 0x130, 0xF, 0xF, true));
}

// Packed Givens gate, in place: ab=(a,b), cs=(c,s) -> (c*a+s*b, c*b-s*a).
__device__ __forceinline__ void gate_pk2(float2 cs, float2& ab) {
  float2 t;
  asm("v_pk_mul_f32 %0, %1, %2 op_sel:[1,1] op_sel_hi:[1,0] neg_hi:[1,0]"
      : "=v"(t)
      : "v"(cs), "v"(ab));
  asm("v_pk_fma_f32 %0, %1, %0, %2 op_sel:[0,0,0] op_sel_hi:[0,1,1]"
      : "+v"(ab)
      : "v"(cs), "v"(t));
}

__device__ __forceinline__ void gate_s(float& a, float& b, float c, float s) {
  float na = fmaf(c, a, s * b);
  float nb = fmaf(c, b, -(s * a));
  a = na;
  b = nb;
}

__device__ __forceinline__ void pair_compute(float2& A, float2& B, float2& C,
                                             float2& D, const float4& q0,
                                             const float4& q1, const float4& q2,
                                             const float4& q3) {
  gate_pk2(make_float2(q0.x, q0.y), A);
  gate_pk2(make_float2(q0.z, q0.w), B);
  gate_pk2(make_float2(q1.x, q1.y), C);
  gate_pk2(make_float2(q1.z, q1.w), D);
  float cl_m1 = dpp_shr1(q3.z);   // left neighbor's (c-1); lane0 -> 0 = identity
  float sl    = dpp_shr1(q3.w);
  float rv0 = dpp_shl1(A.x);      // right neighbor's wire 8L+8 (post-even)
  float lv7 = dpp_shr1(D.y);      // left neighbor's wire 8L-1 (post-even)
  gate_s(A.y, B.x, q2.x, q2.y);
  gate_s(B.y, C.x, q2.z, q2.w);
  gate_s(C.y, D.x, q3.x, q3.y);
  float nv7 = fmaf(q3.w, rv0, fmaf(q3.z, D.y, D.y));   // c = 1 + q3.z
  float nv0 = fmaf(-sl, lv7, fmaf(cl_m1, A.x, A.x));   // c = 1 + cl_m1
  D.y = nv7;
  A.x = nv0;
}

// Wave w issues its 4 of the chunk's 16 DMA loads (regions 4w..4w+3 = pair w).
__device__ __forceinline__ void issue_chunk(const float4* __restrict__ seg,
                                            float4* smem, int c, int bi,
                                            int wave, int lane) {
  const float4* src = seg + c * CH4 + wave * 4 * 64 + lane;
  float4* dst = smem + bi * CH4 + wave * 4 * 64;   // wave-uniform base
#pragma unroll
  for (int j = 0; j < 4; ++j) {
    __builtin_amdgcn_global_load_lds(
        (__attribute__((address_space(1))) uint32_t*)(src + j * 64),
        (__attribute__((address_space(3))) uint32_t*)(dst + j * 64),
        16, 0, 0);
  }
}

// ---------------- kernel 2: two-phase circuit, DMA-shared blocks -----------
__global__ __launch_bounds__(256, 1) void phase_kernel(
    const float* __restrict__ x, const float* __restrict__ W,
    float* __restrict__ T1, float* __restrict__ ML) {
  __shared__ float4 smem[3 * CH4];   // 48 KB, triple-buffered
  const int lane = threadIdx.x & 63;
  const int wave = threadIdx.x >> 6;
  const int b = blockIdx.x;
  const bool late = b >= (BATCH / 4);
  const float4* __restrict__ Wg = (const float4*)W;
  const float4* seg = Wg + (late ? SEGP : 0) * 256;

  // tail pairs 252..254 of the segment -> registers (issued first; retired
  // by the first vmcnt wait)
  float4 Tl[3][4];
#pragma unroll
  for (int pr = 0; pr < 3; ++pr) {
    const float4* pb = seg + (252 + pr) * 256;
#pragma unroll
    for (int q = 0; q < 4; ++q) Tl[pr][q] = pb[q * 64 + lane];
  }
  // prologue DMA: chunks 0, 1
  issue_chunk(seg, smem, 0, 0, wave, lane);
  issue_chunk(seg, smem, 1, 1, wave, lane);

  float2 A, B, C, D;
  if (!late) {
    const int row = b * 4 + wave;
    const float4* xr = (const float4*)(x + row * N_WIRES) + lane * 2;
    float4 x0 = xr[0], x1 = xr[1];
    A = make_float2(x0.x, x0.y); B = make_float2(x0.z, x0.w);
    C = make_float2(x1.x, x1.y); D = make_float2(x1.z, x1.w);
  } else {
    const int u = (b - BATCH / 4) * 4 + wave;
    const int base = lane * 8;
    A = make_float2(base + 0 == u ? 1.f : 0.f, base + 1 == u ? 1.f : 0.f);
    B = make_float2(base + 2 == u ? 1.f : 0.f, base + 3 == u ? 1.f : 0.f);
    C = make_float2(base + 4 == u ? 1.f : 0.f, base + 5 == u ? 1.f : 0.f);
    D = make_float2(base + 6 == u ? 1.f : 0.f, base + 7 == u ? 1.f : 0.f);
  }

  int bsel = 0;
  for (int k = 0; k < NCH - 1; ++k) {      // chunks 0..61
    // retire own loads for chunk k (first iter also retires the 12 tail
    // loads); chunk k+1's 4 stay in flight.
    wait_vm<4>();
    __syncthreads();   // all waves' chunk-k data visible; buffer k-1 free
    const float4* buf = smem + bsel * CH4;
#pragma unroll
    for (int pr = 0; pr < CH; ++pr) {
      pair_compute(A, B, C, D, buf[(pr * 4 + 0) * 64 + lane],
                   buf[(pr * 4 + 1) * 64 + lane],
                   buf[(pr * 4 + 2) * 64 + lane],
                   buf[(pr * 4 + 3) * 64 + lane]);
    }
    if (k + 2 < NCH) {
      int nb = bsel + 2; if (nb >= 3) nb -= 3;
      issue_chunk(seg, smem, k + 2, nb, wave, lane);
    }
    bsel = (bsel == 2) ? 0 : bsel + 1;
  }
  // last chunk (62)
  wait_vm<0>();
  __syncthreads();
  {
    const float4* buf = smem + bsel * CH4;
#pragma unroll
    for (int pr = 0; pr < CH; ++pr) {
      pair_compute(A, B, C, D, buf[(pr * 4 + 0) * 64 + lane],
                   buf[(pr * 4 + 1) * 64 + lane],
                   buf[(pr * 4 + 2) * 64 + lane],
                   buf[(pr * 4 + 3) * 64 + lane]);
    }
  }
  // register tail: pairs 252..254 of the segment
#pragma unroll
  for (int pr = 0; pr < 3; ++pr)
    pair_compute(A, B, C, D, Tl[pr][0], Tl[pr][1], Tl[pr][2], Tl[pr][3]);

  if (!late) {
    const int row = b * 4 + wave;
    float* tr = T1 + row * N_WIRES + lane * 8;
    *(float4*)tr = make_float4(A.x, A.y, B.x, B.y);
    *(float4*)(tr + 4) = make_float4(C.x, C.y, D.x, D.y);
  } else {
    // final even layer t = 1020 (plain (c,s), pre-masked identity)
    float4 f0 = Wg[FINAL4 + lane];
    float4 f1 = Wg[FINAL4 + 64 + lane];
    gate_pk2(make_float2(f0.x, f0.y), A);
    gate_pk2(make_float2(f0.z, f0.w), B);
    gate_pk2(make_float2(f1.x, f1.y), C);
    gate_pk2(make_float2(f1.z, f1.w), D);
    const int u = (b - BATCH / 4) * 4 + wave;
    float* mr = ML + u * N_WIRES + lane * 8;
    *(float4*)mr = make_float4(A.x, A.y, B.x, B.y);
    *(float4*)(mr + 4) = make_float4(C.x, C.y, D.x, D.y);
  }
}

// ---------------- kernel 3: out = T1 * ML + bias (fp32) ----------------
__global__ __launch_bounds__(256) void gemm_kernel(
    const float* __restrict__ T1, const float* __restrict__ ML,
    const float* __restrict__ bias, float* __restrict__ out) {
  __shared__ float a_s[512];
  __shared__ float4 part[128];
  const int tid = threadIdx.x;
  const int j = tid & 127, uh = tid >> 7;   // 2-way u-split x 128 cols
  const int row = blockIdx.x;
  a_s[tid] = T1[row * N_WIRES + tid];
  a_s[tid + 256] = T1[row * N_WIRES + tid + 256];
  __syncthreads();
  const float4* __restrict__ ML4 = (const float4*)ML;
  float4 acc = make_float4(0.f, 0.f, 0.f, 0.f);
  const int u0 = uh * 256;
#pragma unroll 8
  for (int du = 0; du < 256; ++du) {
    float a = a_s[u0 + du];
    float4 m = ML4[(u0 + du) * 128 + j];
    acc.x = fmaf(a, m.x, acc.x);
    acc.y = fmaf(a, m.y, acc.y);
    acc.z = fmaf(a, m.z, acc.z);
    acc.w = fmaf(a, m.w, acc.w);
  }
  if (uh == 1) part[j] = acc;
  __syncthreads();
  if (uh == 0) {
    float4 p = part[j];
    float4 bv = ((const float4*)bias)[j];
    acc.x += p.x + bv.x; acc.y += p.y + bv.y;
    acc.z += p.z + bv.z; acc.w += p.w + bv.w;
    ((float4*)out)[row * 128 + j] = acc;
  }
}

// ---------------- fallback: proven single-phase (R7/R11 structure) ---------
#define PF 5
__global__ __launch_bounds__(64, 1) void circuit_full(
    const float* __restrict__ x, const float* __restrict__ W,
    const float* __restrict__ bias, float* __restrict__ out) {
  const int lane = threadIdx.x;
  const int row = blockIdx.x;
  const float4* __restrict__ Wg = (const float4*)W;

  const float4* pb = Wg;
  float4 R[PF][4];
#pragma unroll
  for (int s = 0; s < PF; ++s) {
    R[s][0] = pb[lane]; R[s][1] = pb[64 + lane];
    R[s][2] = pb[128 + lane]; R[s][3] = pb[192 + lane];
    pb += 256;
  }
  const float4* xr = (const float4*)(x + row * N_WIRES) + lane * 2;
  float4 x0 = xr[0], x1 = xr[1];
  float2 A = make_float2(x0.x, x0.y), B = make_float2(x0.z, x0.w);
  float2 C = make_float2(x1.x, x1.y), D = make_float2(x1.z, x1.w);

  for (int blk = 0; blk < 101; ++blk) {
#pragma unroll
    for (int s = 0; s < PF; ++s) {
      wait_vm<16>();
      pair_compute(A, B, C, D, R[s][0], R[s][1], R[s][2], R[s][3]);
      R[s][0] = pb[lane]; R[s][1] = pb[64 + lane];
      R[s][2] = pb[128 + lane]; R[s][3] = pb[192 + lane];
      pb += 256;
    }
  }
  wait_vm<0>();
#pragma unroll
  for (int s = 0; s < PF; ++s)
    pair_compute(A, B, C, D, R[s][0], R[s][1], R[s][2], R[s][3]);

  float4 f0 = Wg[FINAL4 + lane];
  float4 f1 = Wg[FINAL4 + 64 + lane];
  gate_pk2(make_float2(f0.x, f0.y), A);
  gate_pk2(make_float2(f0.z, f0.w), B);
  gate_pk2(make_float2(f1.x, f1.y), C);
  gate_pk2(make_float2(f1.z, f1.w), D);

  const float* br = bias + lane * 8;
  float4 b0 = *(const float4*)(br);
  float4 b1 = *(const float4*)(br + 4);
  float* orow = out + row * N_WIRES + lane * 8;
  *(float4*)(orow) = make_float4(A.x + b0.x, A.y + b0.y, B.x + b0.z, B.y + b0.w);
  *(float4*)(orow + 4) = make_float4(C.x + b1.x, C.y + b1.y, D.x + b1.z, D.y + b1.w);
}

extern "C" void kernel_launch(void* const* d_in, const int* in_sizes, int n_in,
                              void* d_out, int out_size, void* d_ws,
                              size_t ws_size, hipStream_t stream) {
  const float* x = (const float*)d_in[0];       // (256, 512) f32
  const float* thetas = (const float*)d_in[1];  // (130816,) f32
  const float* bias = (const float*)d_in[2];    // (512,) f32
  float* out = (float*)d_out;                   // (256, 512) f32

  float* W = (float*)d_ws;                      // table: 130688 float4
  const size_t table_bytes = (size_t)TOTAL4 * 16;         // 2,091,008
  const size_t t1_bytes = (size_t)BATCH * N_WIRES * 4;    //   524,288
  const size_t ml_bytes = (size_t)N_WIRES * N_WIRES * 4;  // 1,048,576

  fused_kernel<<<TOTAL2 / 256, 256, 0, stream>>>(thetas, (float2*)W);

  if (ws_size >= table_bytes + t1_bytes + ml_bytes) {
    float* T1 = (float*)((char*)d_ws + table_bytes);
    float* ML = T1 + BATCH * N_WIRES;
    phase_kernel<<<BATCH / 4 + N_WIRES / 4, 256, 0, stream>>>(x, W, T1, ML);
    gemm_kernel<<<BATCH, 256, 0, stream>>>(T1, ML, bias, out);
  } else {
    circuit_full<<<BATCH, 64, 0, stream>>>(x, W, bias, out);
  }
}